// Round 9
// baseline (367.900 us; speedup 1.0000x reference)
//
#include <hip/hip_runtime.h>

#define DIM 256
#define KNN 16
#define SLOPE 0.2f

typedef unsigned short u16;
typedef __attribute__((ext_vector_type(8))) unsigned short u16x8;
typedef __attribute__((ext_vector_type(4))) unsigned short u16x4;
typedef __attribute__((ext_vector_type(8))) short s16x8;
typedef __attribute__((ext_vector_type(4))) float f32x4;

__device__ __forceinline__ float leaky(float x) { return x >= 0.f ? x : SLOPE * x; }
// f32 -> bf16 (RNE) as raw u16; inputs are finite (no NaN handling needed)
__device__ __forceinline__ u16 f2bu(float f) {
    unsigned int u = __float_as_uint(f);
    u = (u + 0x7FFFu + ((u >> 16) & 1u)) >> 16;
    return (u16)u;
}
__device__ __forceinline__ float bu2f(u16 h) {
    return __uint_as_float(((unsigned int)h) << 16);
}

// ---------------------------------------------------------------------------
// Prep: weights -> bf16 in MFMA fragment order so GEMM kernels load B frags
// directly from global (L2-resident broadcast): no LDS staging for B.
// Fragment (ct, ks): lane l holds w[k = ks*32 + (l>>4)*8 + j][col = ct*16 + (l&15)]
// at wT[((ct*8+ks)*64 + l)*8 + j].
// wT1: ct 0..15 = w_res cols, ct 16..19 = w_init cols. wT3: w_fin cols.
__global__ __launch_bounds__(256) void k_prep(
    const float* __restrict__ w_res, const float* __restrict__ w_init,
    const float* __restrict__ w_fin, u16* __restrict__ wT1, u16* __restrict__ wT3)
{
    const int t = blockIdx.x * 256 + threadIdx.x;
    if (t < 20 * 8 * 64) {               // wT1: 10240 entries x 8 u16
        const int lane = t & 63, frag = t >> 6;
        const int ks = frag & 7, ct = frag >> 3;
        const int col = ct * 16 + (lane & 15);
        const int k0 = ks * 32 + (lane >> 4) * 8;
        u16x8 p;
        #pragma unroll
        for (int j = 0; j < 8; ++j) {
            float v = (col < 256) ? w_res[(size_t)(k0 + j) * 256 + col]
                                  : w_init[(size_t)(k0 + j) * 64 + (col - 256)];
            p[j] = f2bu(v);
        }
        *(u16x8*)(wT1 + (size_t)t * 8) = p;
    } else if (t < 20 * 8 * 64 + 16 * 8 * 64) {  // wT3: 8192 entries x 8 u16
        const int u = t - 20 * 8 * 64;
        const int lane = u & 63, frag = u >> 6;
        const int ks = frag & 7, ct = frag >> 3;
        const int col = ct * 16 + (lane & 15);
        const int k0 = ks * 32 + (lane >> 4) * 8;
        u16x8 p;
        #pragma unroll
        for (int j = 0; j < 8; ++j)
            p[j] = f2bu(w_fin[(size_t)(k0 + j) * 256 + col]);
        *(u16x8*)(wT3 + (size_t)u * 8) = p;
    }
}

#define APAD 264  // 256+8 bf16 elems; 528B row stride -> 16B aligned

// ---------------------------------------------------------------------------
// GEMM1 epilogue helper: one 16-col tile (4 row-tiles x 4 regs) of C.
__device__ __forceinline__ void epi_gemm1(
    int base, int N, int ct, int llow, int lhi, const f32x4* acc4,
    const float* __restrict__ b_res, const float* __restrict__ b_init,
    float* __restrict__ resid, u16* __restrict__ a1)
{
    const int col = ct * 16 + llow;
    if (col < 256) {
        const float bias = b_res[col];
        #pragma unroll
        for (int rt = 0; rt < 4; ++rt)
            #pragma unroll
            for (int r = 0; r < 4; ++r) {
                int row = base + rt * 16 + lhi * 4 + r;
                if (row < N)
                    resid[(size_t)row * DIM + col] = leaky(acc4[rt][r] + bias);
            }
    } else {
        const int c2 = col - 256;
        const float bias = b_init[c2];
        #pragma unroll
        for (int rt = 0; rt < 4; ++rt)
            #pragma unroll
            for (int r = 0; r < 4; ++r) {
                int row = base + rt * 16 + lhi * 4 + r;
                if (row < N)
                    a1[(size_t)row * 64 + c2] = f2bu(leaky(acc4[rt][r] + bias));
            }
    }
}

// GEMM1 [R8 proven]: rows=64/block, cols=320 (0..255 -> resid f32 in d_out,
// 256..319 -> a1 bf16), K=256. A full-K in LDS (1 barrier); B frags direct
// from global wT1. Two passes (3+2 col tiles) cut acc VGPR 80->48;
// __launch_bounds__(256,4) -> 4 blocks/CU (LDS 4x33792 = 132KB <= 160KB).
__global__ __launch_bounds__(256, 4) void k_gemm1(
    const float* __restrict__ in, const u16* __restrict__ wT1,
    const float* __restrict__ b_res, const float* __restrict__ b_init,
    float* __restrict__ resid, u16* __restrict__ a1, int N)
{
    __shared__ u16 A_s[64 * APAD];   // 33792 B
    const int t = threadIdx.x;
    const int base = blockIdx.x * 64;

    {
        const int row = t >> 2, seg = t & 3;
        const int grow = min(base + row, N - 1);
        const float* src = in + (size_t)grow * DIM + seg * 64;
        u16* dst = &A_s[row * APAD + seg * 64];
        #pragma unroll
        for (int j = 0; j < 8; ++j) {
            float4 f0 = *(const float4*)(src + j * 8);
            float4 f1 = *(const float4*)(src + j * 8 + 4);
            u16x8 p;
            p[0] = f2bu(f0.x); p[1] = f2bu(f0.y); p[2] = f2bu(f0.z); p[3] = f2bu(f0.w);
            p[4] = f2bu(f1.x); p[5] = f2bu(f1.y); p[6] = f2bu(f1.z); p[7] = f2bu(f1.w);
            *(u16x8*)(dst + j * 8) = p;
        }
    }
    __syncthreads();  // the only barrier

    const int w = t >> 6, lane = t & 63;
    const int llow = lane & 15, lhi = lane >> 4;

    // ---- pass 0: local col tiles 0..2 ----
    {
        f32x4 acc[3][4];
        #pragma unroll
        for (int i = 0; i < 3; ++i)
            #pragma unroll
            for (int j = 0; j < 4; ++j)
                acc[i][j] = (f32x4){0.f, 0.f, 0.f, 0.f};
        for (int ks = 0; ks < 8; ++ks) {
            s16x8 bfrag[3];
            #pragma unroll
            for (int ci = 0; ci < 3; ++ci) {
                const int ct = w * 5 + ci;
                bfrag[ci] = *(const s16x8*)(wT1 + ((size_t)(ct * 8 + ks) * 64 + lane) * 8);
            }
            s16x8 afrag[4];
            #pragma unroll
            for (int rt = 0; rt < 4; ++rt)
                afrag[rt] = *(const s16x8*)(&A_s[(rt * 16 + llow) * APAD + ks * 32 + lhi * 8]);
            #pragma unroll
            for (int ci = 0; ci < 3; ++ci)
                #pragma unroll
                for (int rt = 0; rt < 4; ++rt)
                    acc[ci][rt] = __builtin_amdgcn_mfma_f32_16x16x32_bf16(
                        afrag[rt], bfrag[ci], acc[ci][rt], 0, 0, 0);
        }
        #pragma unroll
        for (int ci = 0; ci < 3; ++ci)
            epi_gemm1(base, N, w * 5 + ci, llow, lhi, acc[ci], b_res, b_init, resid, a1);
    }
    // ---- pass 1: local col tiles 3..4 ----
    {
        f32x4 acc[2][4];
        #pragma unroll
        for (int i = 0; i < 2; ++i)
            #pragma unroll
            for (int j = 0; j < 4; ++j)
                acc[i][j] = (f32x4){0.f, 0.f, 0.f, 0.f};
        for (int ks = 0; ks < 8; ++ks) {
            s16x8 bfrag[2];
            #pragma unroll
            for (int ci = 0; ci < 2; ++ci) {
                const int ct = w * 5 + 3 + ci;
                bfrag[ci] = *(const s16x8*)(wT1 + ((size_t)(ct * 8 + ks) * 64 + lane) * 8);
            }
            s16x8 afrag[4];
            #pragma unroll
            for (int rt = 0; rt < 4; ++rt)
                afrag[rt] = *(const s16x8*)(&A_s[(rt * 16 + llow) * APAD + ks * 32 + lhi * 8]);
            #pragma unroll
            for (int ci = 0; ci < 2; ++ci)
                #pragma unroll
                for (int rt = 0; rt < 4; ++rt)
                    acc[ci][rt] = __builtin_amdgcn_mfma_f32_16x16x32_bf16(
                        afrag[rt], bfrag[ci], acc[ci][rt], 0, 0, 0);
        }
        #pragma unroll
        for (int ci = 0; ci < 2; ++ci)
            epi_gemm1(base, N, w * 5 + 3 + ci, llow, lhi, acc[ci], b_res, b_init, resid, a1);
    }
}

// ---------------------------------------------------------------------------
// LFA1 [R8 proven]: 32 points/block, 8 lanes/pt, u16x8 gather loads (16B/lane,
// 8 lanes cover the 128B a1 row), k unrolled x2. MLP weights in regs.
__global__ __launch_bounds__(256) void k_lfa1(
    const float* __restrict__ geom, const int* __restrict__ idx,
    const float* __restrict__ w_g1, const float* __restrict__ b_g1,
    const u16* __restrict__ a1, u16* __restrict__ a2, int N)
{
    __shared__ float geom_s[32 * KNN * 4];  // 8 KB
    __shared__ int idx_s[32 * KNN];         // 2 KB
    const int t = threadIdx.x;
    const int base = blockIdx.x * 32;

    {
        size_t mx = (size_t)N * 64 - 4;
        size_t off0 = (size_t)base * 64 + t * 4;
        size_t off1 = off0 + 1024;
        if (off0 > mx) off0 = mx;
        if (off1 > mx) off1 = mx;
        *(float4*)&geom_s[t * 4] = *(const float4*)(geom + off0);
        *(float4*)&geom_s[1024 + t * 4] = *(const float4*)(geom + off1);
        const int imx = N * KNN - 1;
        idx_s[t] = idx[min(base * KNN + t, imx)];
        idx_s[t + 256] = idx[min(base * KNN + 256 + t, imx)];
    }
    __syncthreads();

    const int pt = t >> 3, s = t & 7;
    const int n = base + pt;

    float wr[4][8], bb[8];
    #pragma unroll
    for (int r = 0; r < 4; ++r)
        #pragma unroll
        for (int j = 0; j < 8; ++j)
            wr[r][j] = w_g1[r * 64 + s * 8 + j];
    #pragma unroll
    for (int j = 0; j < 8; ++j) bb[j] = b_g1[s * 8 + j];

    float accM[8];
    #pragma unroll
    for (int j = 0; j < 8; ++j) accM[j] = 0.f;
    const float4* g4 = (const float4*)&geom_s[pt * 64];
    #pragma unroll
    for (int k = 0; k < KNN; ++k) {
        float4 g = g4[k];
        #pragma unroll
        for (int j = 0; j < 8; ++j)
            accM[j] += leaky(g.x * wr[0][j] + g.y * wr[1][j] + g.z * wr[2][j] + g.w * wr[3][j] + bb[j]);
    }

    float accG[8];
    #pragma unroll
    for (int j = 0; j < 8; ++j) accG[j] = 0.f;
    #pragma unroll
    for (int k = 0; k < KNN; k += 2) {
        u16x8 u0 = *(const u16x8*)(a1 + (size_t)idx_s[pt * KNN + k] * 64 + s * 8);
        u16x8 u1 = *(const u16x8*)(a1 + (size_t)idx_s[pt * KNN + k + 1] * 64 + s * 8);
        #pragma unroll
        for (int j = 0; j < 8; ++j) accG[j] += bu2f(u0[j]) + bu2f(u1[j]);
    }

    if (n < N) {
        u16x8 pm, pg;
        #pragma unroll
        for (int j = 0; j < 8; ++j) {
            pm[j] = f2bu(accM[j] * 0.0625f);
            pg[j] = f2bu(accG[j] * 0.0625f);
        }
        *(u16x8*)(a2 + (size_t)n * 128 + s * 8) = pm;
        *(u16x8*)(a2 + (size_t)n * 128 + 64 + s * 8) = pg;
    }
}

// ---------------------------------------------------------------------------
// LFA2 + final GEMM fused, T14 async-stage pipeline: 64 points/block.
// Each thread carries BOTH roles: MLP (c = t&127, h = t>>7; 32 pts) and
// gather (pt = t>>2, q = t&3; coalesced 64B/pt/step). The gather's 16 rows
// are double-buffered 2-at-a-time: loads issued BEFORE each 4-point MLP
// chunk (~900 cy VALU) and consumed after it -> L2/HBM latency hidden under
// the MLP instead of serial. All buffers statically indexed (full unroll).
// 2 blocks/CU (LDS 54272) protects a2's L2 reuse (R2/3/7 falsifiers).
__global__ __launch_bounds__(256) void k_lfa2_fin(
    const float* __restrict__ geom, const int* __restrict__ idx,
    const float* __restrict__ w_g2, const float* __restrict__ b_g2,
    const u16* __restrict__ a2, const u16* __restrict__ wT3,
    const float* __restrict__ b_fin, float* __restrict__ out, int N)
{
    __shared__ u16 a3_s[64 * APAD];         // 33792 B
    __shared__ float geom_s[64 * KNN * 4];  // 16384 B
    __shared__ int idx_s[64 * KNN];         // 4096 B
    const int t = threadIdx.x;
    const int base = blockIdx.x * 64;

    // stage geom + idx (clamped; clamped rows are >= N and never stored)
    {
        size_t mx = (size_t)N * 64 - 4;
        #pragma unroll
        for (int j = 0; j < 4; ++j) {
            size_t off = (size_t)base * 64 + t * 4 + j * 1024;
            if (off > mx) off = mx;
            *(float4*)&geom_s[t * 4 + j * 1024] = *(const float4*)(geom + off);
        }
        int imx = N * KNN - 1;
        #pragma unroll
        for (int j = 0; j < 4; ++j) {
            int off = base * KNN + t + j * 256;
            idx_s[t + j * 256] = idx[min(off, imx)];
        }
    }
    __syncthreads();

    // roles
    const int c = t & 127, h = t >> 7;       // MLP: col c, points h*32..h*32+31
    const int pt = t >> 2, q = t & 3;        // gather: point pt, quarter q

    const float w0 = w_g2[c], w1 = w_g2[128 + c], w2 = w_g2[256 + c],
                w3 = w_g2[384 + c], bbm = b_g2[c];

    int ind[16];
    #pragma unroll
    for (int k = 0; k < 16; ++k) ind[k] = idx_s[pt * KNN + k];

    float gacc[4][8];
    #pragma unroll
    for (int j = 0; j < 4; ++j)
        #pragma unroll
        for (int i = 0; i < 8; ++i) gacc[j][i] = 0.f;

    u16x8 bufA[2][4], bufB[2][4];
    // prologue: issue rows k=0,1 into phase 0
    {
        const u16* r0 = a2 + (size_t)ind[0] * 128;
        const u16* r1 = a2 + (size_t)ind[1] * 128;
        #pragma unroll
        for (int j = 0; j < 4; ++j) bufA[0][j] = *(const u16x8*)(r0 + j * 32 + q * 8);
        #pragma unroll
        for (int j = 0; j < 4; ++j) bufB[0][j] = *(const u16x8*)(r1 + j * 32 + q * 8);
    }

    #pragma unroll
    for (int kb = 0; kb < 8; ++kb) {
        const int cur = kb & 1, nxt = cur ^ 1;
        // issue next pair of gather rows (in flight across the MLP chunk)
        if (kb < 7) {
            const u16* r0 = a2 + (size_t)ind[2 * kb + 2] * 128;
            const u16* r1 = a2 + (size_t)ind[2 * kb + 3] * 128;
            #pragma unroll
            for (int j = 0; j < 4; ++j) bufA[nxt][j] = *(const u16x8*)(r0 + j * 32 + q * 8);
            #pragma unroll
            for (int j = 0; j < 4; ++j) bufB[nxt][j] = *(const u16x8*)(r1 + j * 32 + q * 8);
        }
        // MLP chunk: 4 points (VALU, covers the outstanding loads' latency)
        #pragma unroll
        for (int pp = 0; pp < 4; ++pp) {
            const int p = h * 32 + kb * 4 + pp;
            float acc = 0.f;
            const float4* g4 = (const float4*)&geom_s[p * 64];
            #pragma unroll
            for (int k = 0; k < KNN; ++k) {
                float4 g = g4[k];
                acc += leaky(g.x * w0 + g.y * w1 + g.z * w2 + g.w * w3 + bbm);
            }
            a3_s[p * APAD + c] = f2bu(acc * 0.0625f);
        }
        // consume current pair
        #pragma unroll
        for (int j = 0; j < 4; ++j)
            #pragma unroll
            for (int i = 0; i < 8; ++i)
                gacc[j][i] += bu2f(bufA[cur][j][i]) + bu2f(bufB[cur][j][i]);
    }

    // write gather result -> a3 cols 128..255
    #pragma unroll
    for (int j = 0; j < 4; ++j) {
        u16x8 p;
        #pragma unroll
        for (int i = 0; i < 8; ++i) p[i] = f2bu(gacc[j][i] * 0.0625f);
        *(u16x8*)(&a3_s[pt * APAD + 128 + j * 32 + q * 8]) = p;
    }
    __syncthreads();  // a3_s complete; MFMA loop below is barrier-free

    f32x4 acc[4][4];
    #pragma unroll
    for (int i = 0; i < 4; ++i)
        #pragma unroll
        for (int j = 0; j < 4; ++j)
            acc[i][j] = (f32x4){0.f, 0.f, 0.f, 0.f};

    const int w = t >> 6, lane = t & 63;
    const int llow = lane & 15, lhi = lane >> 4;

    for (int ks = 0; ks < 8; ++ks) {
        s16x8 bfrag[4];
        #pragma unroll
        for (int ci = 0; ci < 4; ++ci) {
            const int ct = w * 4 + ci;
            bfrag[ci] = *(const s16x8*)(wT3 + ((size_t)(ct * 8 + ks) * 64 + lane) * 8);
        }
        s16x8 afrag[4];
        #pragma unroll
        for (int rt = 0; rt < 4; ++rt)
            afrag[rt] = *(const s16x8*)(&a3_s[(rt * 16 + llow) * APAD + ks * 32 + lhi * 8]);
        #pragma unroll
        for (int ci = 0; ci < 4; ++ci)
            #pragma unroll
            for (int rt = 0; rt < 4; ++rt)
                acc[rt][ci] = __builtin_amdgcn_mfma_f32_16x16x32_bf16(
                    afrag[rt], bfrag[ci], acc[rt][ci], 0, 0, 0);
    }

    #pragma unroll
    for (int ci = 0; ci < 4; ++ci) {
        const int ct = w * 4 + ci;
        const int col = ct * 16 + llow;
        const float bias = b_fin[col];
        #pragma unroll
        for (int rt = 0; rt < 4; ++rt)
            #pragma unroll
            for (int r = 0; r < 4; ++r) {
                int row = base + rt * 16 + lhi * 4 + r;
                if (row < N) {
                    size_t o = (size_t)row * DIM + col;
                    out[o] = leaky(acc[rt][ci][r] + bias) + out[o];
                }
            }
    }
}

// ---------------------------------------------------------------------------
extern "C" void kernel_launch(void* const* d_in, const int* in_sizes, int n_in,
                              void* d_out, int out_size, void* d_ws, size_t ws_size,
                              hipStream_t stream) {
    const float* in    = (const float*)d_in[0];
    const float* geom  = (const float*)d_in[1];
    const int*   idx   = (const int*)d_in[2];
    const float* w_res = (const float*)d_in[3];
    const float* b_res = (const float*)d_in[4];
    const float* w_init= (const float*)d_in[5];
    const float* b_init= (const float*)d_in[6];
    const float* w_g1  = (const float*)d_in[7];
    const float* b_g1  = (const float*)d_in[8];
    const float* w_g2  = (const float*)d_in[9];
    const float* b_g2  = (const float*)d_in[10];
    const float* w_fin = (const float*)d_in[11];
    const float* b_fin = (const float*)d_in[12];
    float* out = (float*)d_out;

    const int N = in_sizes[0] / DIM;  // 50000

    // ws: a1 N*64 bf16 | a2 N*128 bf16 | wT1 320*256 bf16 | wT3 256*256 bf16
    char* ws = (char*)d_ws;
    u16* a1  = (u16*)ws;
    u16* a2  = a1 + (size_t)N * 64;
    u16* wT1 = a2 + (size_t)N * 128;
    u16* wT3 = wT1 + 320 * 256;

    k_prep<<<72, 256, 0, stream>>>(w_res, w_init, w_fin, wT1, wT3);
    k_gemm1<<<(N + 63) / 64, 256, 0, stream>>>(in, wT1, b_res, b_init, out, a1, N);
    k_lfa1<<<(N + 31) / 32, 256, 0, stream>>>(geom, idx, w_g1, b_g1, a1, a2, N);
    k_lfa2_fin<<<(N + 63) / 64, 256, 0, stream>>>(geom, idx, w_g2, b_g2, a2, wT3, b_fin, out, N);
}

// Round 10
// 339.566 us; speedup vs baseline: 1.0834x; 1.0834x over previous
//
#include <hip/hip_runtime.h>

#define DIM 256
#define KNN 16
#define SLOPE 0.2f

typedef unsigned short u16;
typedef __attribute__((ext_vector_type(8))) unsigned short u16x8;
typedef __attribute__((ext_vector_type(4))) unsigned short u16x4;
typedef __attribute__((ext_vector_type(8))) short s16x8;
typedef __attribute__((ext_vector_type(4))) float f32x4;

__device__ __forceinline__ float leaky(float x) { return x >= 0.f ? x : SLOPE * x; }
// f32 -> bf16 (RNE) as raw u16; inputs are finite (no NaN handling needed)
__device__ __forceinline__ u16 f2bu(float f) {
    unsigned int u = __float_as_uint(f);
    u = (u + 0x7FFFu + ((u >> 16) & 1u)) >> 16;
    return (u16)u;
}
__device__ __forceinline__ float bu2f(u16 h) {
    return __uint_as_float(((unsigned int)h) << 16);
}

// ---------------------------------------------------------------------------
// Prep: weights -> bf16 in MFMA fragment order so GEMM kernels load B frags
// directly from global (L2-resident broadcast): no LDS staging for B.
// Fragment (ct, ks): lane l holds w[k = ks*32 + (l>>4)*8 + j][col = ct*16 + (l&15)]
// at wT[((ct*8+ks)*64 + l)*8 + j].
// wT1: ct 0..15 = w_res cols, ct 16..19 = w_init cols. wT3: w_fin cols.
__global__ __launch_bounds__(256) void k_prep(
    const float* __restrict__ w_res, const float* __restrict__ w_init,
    const float* __restrict__ w_fin, u16* __restrict__ wT1, u16* __restrict__ wT3)
{
    const int t = blockIdx.x * 256 + threadIdx.x;
    if (t < 20 * 8 * 64) {               // wT1: 10240 entries x 8 u16
        const int lane = t & 63, frag = t >> 6;
        const int ks = frag & 7, ct = frag >> 3;
        const int col = ct * 16 + (lane & 15);
        const int k0 = ks * 32 + (lane >> 4) * 8;
        u16x8 p;
        #pragma unroll
        for (int j = 0; j < 8; ++j) {
            float v = (col < 256) ? w_res[(size_t)(k0 + j) * 256 + col]
                                  : w_init[(size_t)(k0 + j) * 64 + (col - 256)];
            p[j] = f2bu(v);
        }
        *(u16x8*)(wT1 + (size_t)t * 8) = p;
    } else if (t < 20 * 8 * 64 + 16 * 8 * 64) {  // wT3: 8192 entries x 8 u16
        const int u = t - 20 * 8 * 64;
        const int lane = u & 63, frag = u >> 6;
        const int ks = frag & 7, ct = frag >> 3;
        const int col = ct * 16 + (lane & 15);
        const int k0 = ks * 32 + (lane >> 4) * 8;
        u16x8 p;
        #pragma unroll
        for (int j = 0; j < 8; ++j)
            p[j] = f2bu(w_fin[(size_t)(k0 + j) * 256 + col]);
        *(u16x8*)(wT3 + (size_t)u * 8) = p;
    }
}

#define APAD 264  // 256+8 bf16 elems; 528B row stride -> 16B aligned

// ---------------------------------------------------------------------------
// GEMM1 epilogue helper: one 16-col tile (4 row-tiles x 4 regs) of C.
__device__ __forceinline__ void epi_gemm1(
    int base, int N, int ct, int llow, int lhi, const f32x4* acc4,
    const float* __restrict__ b_res, const float* __restrict__ b_init,
    float* __restrict__ resid, u16* __restrict__ a1)
{
    const int col = ct * 16 + llow;
    if (col < 256) {
        const float bias = b_res[col];
        #pragma unroll
        for (int rt = 0; rt < 4; ++rt)
            #pragma unroll
            for (int r = 0; r < 4; ++r) {
                int row = base + rt * 16 + lhi * 4 + r;
                if (row < N)
                    resid[(size_t)row * DIM + col] = leaky(acc4[rt][r] + bias);
            }
    } else {
        const int c2 = col - 256;
        const float bias = b_init[c2];
        #pragma unroll
        for (int rt = 0; rt < 4; ++rt)
            #pragma unroll
            for (int r = 0; r < 4; ++r) {
                int row = base + rt * 16 + lhi * 4 + r;
                if (row < N)
                    a1[(size_t)row * 64 + c2] = f2bu(leaky(acc4[rt][r] + bias));
            }
    }
}

// GEMM1 [R8 proven]: rows=64/block, cols=320 (0..255 -> resid f32 in d_out,
// 256..319 -> a1 bf16), K=256. A full-K in LDS (1 barrier); B frags direct
// from global wT1. Two passes (3+2 col tiles) cut acc VGPR 80->48;
// __launch_bounds__(256,4) -> 4 blocks/CU (LDS 4x33792 = 132KB <= 160KB).
__global__ __launch_bounds__(256, 4) void k_gemm1(
    const float* __restrict__ in, const u16* __restrict__ wT1,
    const float* __restrict__ b_res, const float* __restrict__ b_init,
    float* __restrict__ resid, u16* __restrict__ a1, int N)
{
    __shared__ u16 A_s[64 * APAD];   // 33792 B
    const int t = threadIdx.x;
    const int base = blockIdx.x * 64;

    {
        const int row = t >> 2, seg = t & 3;
        const int grow = min(base + row, N - 1);
        const float* src = in + (size_t)grow * DIM + seg * 64;
        u16* dst = &A_s[row * APAD + seg * 64];
        #pragma unroll
        for (int j = 0; j < 8; ++j) {
            float4 f0 = *(const float4*)(src + j * 8);
            float4 f1 = *(const float4*)(src + j * 8 + 4);
            u16x8 p;
            p[0] = f2bu(f0.x); p[1] = f2bu(f0.y); p[2] = f2bu(f0.z); p[3] = f2bu(f0.w);
            p[4] = f2bu(f1.x); p[5] = f2bu(f1.y); p[6] = f2bu(f1.z); p[7] = f2bu(f1.w);
            *(u16x8*)(dst + j * 8) = p;
        }
    }
    __syncthreads();  // the only barrier

    const int w = t >> 6, lane = t & 63;
    const int llow = lane & 15, lhi = lane >> 4;

    // ---- pass 0: local col tiles 0..2 ----
    {
        f32x4 acc[3][4];
        #pragma unroll
        for (int i = 0; i < 3; ++i)
            #pragma unroll
            for (int j = 0; j < 4; ++j)
                acc[i][j] = (f32x4){0.f, 0.f, 0.f, 0.f};
        for (int ks = 0; ks < 8; ++ks) {
            s16x8 bfrag[3];
            #pragma unroll
            for (int ci = 0; ci < 3; ++ci) {
                const int ct = w * 5 + ci;
                bfrag[ci] = *(const s16x8*)(wT1 + ((size_t)(ct * 8 + ks) * 64 + lane) * 8);
            }
            s16x8 afrag[4];
            #pragma unroll
            for (int rt = 0; rt < 4; ++rt)
                afrag[rt] = *(const s16x8*)(&A_s[(rt * 16 + llow) * APAD + ks * 32 + lhi * 8]);
            #pragma unroll
            for (int ci = 0; ci < 3; ++ci)
                #pragma unroll
                for (int rt = 0; rt < 4; ++rt)
                    acc[ci][rt] = __builtin_amdgcn_mfma_f32_16x16x32_bf16(
                        afrag[rt], bfrag[ci], acc[ci][rt], 0, 0, 0);
        }
        #pragma unroll
        for (int ci = 0; ci < 3; ++ci)
            epi_gemm1(base, N, w * 5 + ci, llow, lhi, acc[ci], b_res, b_init, resid, a1);
    }
    // ---- pass 1: local col tiles 3..4 ----
    {
        f32x4 acc[2][4];
        #pragma unroll
        for (int i = 0; i < 2; ++i)
            #pragma unroll
            for (int j = 0; j < 4; ++j)
                acc[i][j] = (f32x4){0.f, 0.f, 0.f, 0.f};
        for (int ks = 0; ks < 8; ++ks) {
            s16x8 bfrag[2];
            #pragma unroll
            for (int ci = 0; ci < 2; ++ci) {
                const int ct = w * 5 + 3 + ci;
                bfrag[ci] = *(const s16x8*)(wT1 + ((size_t)(ct * 8 + ks) * 64 + lane) * 8);
            }
            s16x8 afrag[4];
            #pragma unroll
            for (int rt = 0; rt < 4; ++rt)
                afrag[rt] = *(const s16x8*)(&A_s[(rt * 16 + llow) * APAD + ks * 32 + lhi * 8]);
            #pragma unroll
            for (int ci = 0; ci < 2; ++ci)
                #pragma unroll
                for (int rt = 0; rt < 4; ++rt)
                    acc[ci][rt] = __builtin_amdgcn_mfma_f32_16x16x32_bf16(
                        afrag[rt], bfrag[ci], acc[ci][rt], 0, 0, 0);
        }
        #pragma unroll
        for (int ci = 0; ci < 2; ++ci)
            epi_gemm1(base, N, w * 5 + 3 + ci, llow, lhi, acc[ci], b_res, b_init, resid, a1);
    }
}

// ---------------------------------------------------------------------------
// LFA1 [R8 proven]: 32 points/block, 8 lanes/pt, u16x8 gather loads (16B/lane,
// 8 lanes cover the 128B a1 row), k unrolled x2. MLP weights in regs.
__global__ __launch_bounds__(256) void k_lfa1(
    const float* __restrict__ geom, const int* __restrict__ idx,
    const float* __restrict__ w_g1, const float* __restrict__ b_g1,
    const u16* __restrict__ a1, u16* __restrict__ a2, int N)
{
    __shared__ float geom_s[32 * KNN * 4];  // 8 KB
    __shared__ int idx_s[32 * KNN];         // 2 KB
    const int t = threadIdx.x;
    const int base = blockIdx.x * 32;

    {
        size_t mx = (size_t)N * 64 - 4;
        size_t off0 = (size_t)base * 64 + t * 4;
        size_t off1 = off0 + 1024;
        if (off0 > mx) off0 = mx;
        if (off1 > mx) off1 = mx;
        *(float4*)&geom_s[t * 4] = *(const float4*)(geom + off0);
        *(float4*)&geom_s[1024 + t * 4] = *(const float4*)(geom + off1);
        const int imx = N * KNN - 1;
        idx_s[t] = idx[min(base * KNN + t, imx)];
        idx_s[t + 256] = idx[min(base * KNN + 256 + t, imx)];
    }
    __syncthreads();

    const int pt = t >> 3, s = t & 7;
    const int n = base + pt;

    float wr[4][8], bb[8];
    #pragma unroll
    for (int r = 0; r < 4; ++r)
        #pragma unroll
        for (int j = 0; j < 8; ++j)
            wr[r][j] = w_g1[r * 64 + s * 8 + j];
    #pragma unroll
    for (int j = 0; j < 8; ++j) bb[j] = b_g1[s * 8 + j];

    float accM[8];
    #pragma unroll
    for (int j = 0; j < 8; ++j) accM[j] = 0.f;
    const float4* g4 = (const float4*)&geom_s[pt * 64];
    #pragma unroll
    for (int k = 0; k < KNN; ++k) {
        float4 g = g4[k];
        #pragma unroll
        for (int j = 0; j < 8; ++j)
            accM[j] += leaky(g.x * wr[0][j] + g.y * wr[1][j] + g.z * wr[2][j] + g.w * wr[3][j] + bb[j]);
    }

    float accG[8];
    #pragma unroll
    for (int j = 0; j < 8; ++j) accG[j] = 0.f;
    #pragma unroll
    for (int k = 0; k < KNN; k += 2) {
        u16x8 u0 = *(const u16x8*)(a1 + (size_t)idx_s[pt * KNN + k] * 64 + s * 8);
        u16x8 u1 = *(const u16x8*)(a1 + (size_t)idx_s[pt * KNN + k + 1] * 64 + s * 8);
        #pragma unroll
        for (int j = 0; j < 8; ++j) accG[j] += bu2f(u0[j]) + bu2f(u1[j]);
    }

    if (n < N) {
        u16x8 pm, pg;
        #pragma unroll
        for (int j = 0; j < 8; ++j) {
            pm[j] = f2bu(accM[j] * 0.0625f);
            pg[j] = f2bu(accG[j] * 0.0625f);
        }
        *(u16x8*)(a2 + (size_t)n * 128 + s * 8) = pm;
        *(u16x8*)(a2 + (size_t)n * 128 + 64 + s * 8) = pg;
    }
}

// ---------------------------------------------------------------------------
// LFA2 + final GEMM fused, WAVE-ROLE SPLIT: 64 points/block.
// After staging, waves 0-1 (t<128) run the geom-MLP for ALL 64 points
// (thread = col c = t; pure VALU + LDS-broadcast reads), while waves 2-3
// run the a2-gather for ALL 64 points (4 lanes/pt, two 32-pt passes,
// coalesced 64B/pt/step, 2 rows in flight). The CU scheduler interleaves
// the roles per-SIMD: gather latency hides under MLP VALU with ZERO extra
// per-thread registers (R9's pipeline died of VGPR=176; this splits state
// across waves instead). MFMA + epilogue unchanged, all waves.
// 2 blocks/CU (LDS 54272) protects a2's L2 reuse (R2/3/7 falsifiers).
__global__ __launch_bounds__(256) void k_lfa2_fin(
    const float* __restrict__ geom, const int* __restrict__ idx,
    const float* __restrict__ w_g2, const float* __restrict__ b_g2,
    const u16* __restrict__ a2, const u16* __restrict__ wT3,
    const float* __restrict__ b_fin, float* __restrict__ out, int N)
{
    __shared__ u16 a3_s[64 * APAD];         // 33792 B
    __shared__ float geom_s[64 * KNN * 4];  // 16384 B
    __shared__ int idx_s[64 * KNN];         // 4096 B
    const int t = threadIdx.x;
    const int base = blockIdx.x * 64;

    // stage geom + idx (clamped; clamped rows are >= N and never stored)
    {
        size_t mx = (size_t)N * 64 - 4;
        #pragma unroll
        for (int j = 0; j < 4; ++j) {
            size_t off = (size_t)base * 64 + t * 4 + j * 1024;
            if (off > mx) off = mx;
            *(float4*)&geom_s[t * 4 + j * 1024] = *(const float4*)(geom + off);
        }
        int imx = N * KNN - 1;
        #pragma unroll
        for (int j = 0; j < 4; ++j) {
            int off = base * KNN + t + j * 256;
            idx_s[t + j * 256] = idx[min(off, imx)];
        }
    }
    __syncthreads();

    if (t < 128) {
        // ---- MLP role (waves 0-1): col c = t, all 64 points ----
        const int c = t;
        const float w0 = w_g2[c], w1 = w_g2[128 + c], w2 = w_g2[256 + c],
                    w3 = w_g2[384 + c], bbm = b_g2[c];
        for (int p = 0; p < 64; ++p) {
            float acc = 0.f;
            const float4* g4 = (const float4*)&geom_s[p * 64];
            #pragma unroll
            for (int k = 0; k < KNN; ++k) {
                float4 g = g4[k];
                acc += leaky(g.x * w0 + g.y * w1 + g.z * w2 + g.w * w3 + bbm);
            }
            a3_s[p * APAD + c] = f2bu(acc * 0.0625f);
        }
    } else {
        // ---- gather role (waves 2-3): 4 lanes/pt, two 32-pt passes ----
        const int tg = t - 128;
        const int q = tg & 3, pt0 = tg >> 2;  // pt0 in 0..31
        #pragma unroll
        for (int pass = 0; pass < 2; ++pass) {
            const int pt = pt0 + pass * 32;
            float acc[4][8];
            #pragma unroll
            for (int j = 0; j < 4; ++j)
                #pragma unroll
                for (int i = 0; i < 8; ++i) acc[j][i] = 0.f;
            for (int k = 0; k < KNN; k += 2) {  // 2 rows in flight
                const u16* r0 = a2 + (size_t)idx_s[pt * KNN + k] * 128;
                const u16* r1 = a2 + (size_t)idx_s[pt * KNN + k + 1] * 128;
                u16x8 u0[4], u1[4];
                #pragma unroll
                for (int j = 0; j < 4; ++j) {
                    u0[j] = *(const u16x8*)(r0 + j * 32 + q * 8);
                    u1[j] = *(const u16x8*)(r1 + j * 32 + q * 8);
                }
                #pragma unroll
                for (int j = 0; j < 4; ++j)
                    #pragma unroll
                    for (int i = 0; i < 8; ++i)
                        acc[j][i] += bu2f(u0[j][i]) + bu2f(u1[j][i]);
            }
            #pragma unroll
            for (int j = 0; j < 4; ++j) {
                u16x8 p;
                #pragma unroll
                for (int i = 0; i < 8; ++i) p[i] = f2bu(acc[j][i] * 0.0625f);
                *(u16x8*)(&a3_s[pt * APAD + 128 + j * 32 + q * 8]) = p;
            }
        }
    }
    __syncthreads();  // a3_s complete; MFMA loop below is barrier-free

    f32x4 acc[4][4];
    #pragma unroll
    for (int i = 0; i < 4; ++i)
        #pragma unroll
        for (int j = 0; j < 4; ++j)
            acc[i][j] = (f32x4){0.f, 0.f, 0.f, 0.f};

    const int w = t >> 6, lane = t & 63;
    const int llow = lane & 15, lhi = lane >> 4;

    for (int ks = 0; ks < 8; ++ks) {
        s16x8 bfrag[4];
        #pragma unroll
        for (int ci = 0; ci < 4; ++ci) {
            const int ct = w * 4 + ci;
            bfrag[ci] = *(const s16x8*)(wT3 + ((size_t)(ct * 8 + ks) * 64 + lane) * 8);
        }
        s16x8 afrag[4];
        #pragma unroll
        for (int rt = 0; rt < 4; ++rt)
            afrag[rt] = *(const s16x8*)(&a3_s[(rt * 16 + llow) * APAD + ks * 32 + lhi * 8]);
        #pragma unroll
        for (int ci = 0; ci < 4; ++ci)
            #pragma unroll
            for (int rt = 0; rt < 4; ++rt)
                acc[rt][ci] = __builtin_amdgcn_mfma_f32_16x16x32_bf16(
                    afrag[rt], bfrag[ci], acc[rt][ci], 0, 0, 0);
    }

    #pragma unroll
    for (int ci = 0; ci < 4; ++ci) {
        const int ct = w * 4 + ci;
        const int col = ct * 16 + llow;
        const float bias = b_fin[col];
        #pragma unroll
        for (int rt = 0; rt < 4; ++rt)
            #pragma unroll
            for (int r = 0; r < 4; ++r) {
                int row = base + rt * 16 + lhi * 4 + r;
                if (row < N) {
                    size_t o = (size_t)row * DIM + col;
                    out[o] = leaky(acc[rt][ci][r] + bias) + out[o];
                }
            }
    }
}

// ---------------------------------------------------------------------------
extern "C" void kernel_launch(void* const* d_in, const int* in_sizes, int n_in,
                              void* d_out, int out_size, void* d_ws, size_t ws_size,
                              hipStream_t stream) {
    const float* in    = (const float*)d_in[0];
    const float* geom  = (const float*)d_in[1];
    const int*   idx   = (const int*)d_in[2];
    const float* w_res = (const float*)d_in[3];
    const float* b_res = (const float*)d_in[4];
    const float* w_init= (const float*)d_in[5];
    const float* b_init= (const float*)d_in[6];
    const float* w_g1  = (const float*)d_in[7];
    const float* b_g1  = (const float*)d_in[8];
    const float* w_g2  = (const float*)d_in[9];
    const float* b_g2  = (const float*)d_in[10];
    const float* w_fin = (const float*)d_in[11];
    const float* b_fin = (const float*)d_in[12];
    float* out = (float*)d_out;

    const int N = in_sizes[0] / DIM;  // 50000

    // ws: a1 N*64 bf16 | a2 N*128 bf16 | wT1 320*256 bf16 | wT3 256*256 bf16
    char* ws = (char*)d_ws;
    u16* a1  = (u16*)ws;
    u16* a2  = a1 + (size_t)N * 64;
    u16* wT1 = a2 + (size_t)N * 128;
    u16* wT3 = wT1 + 320 * 256;

    k_prep<<<72, 256, 0, stream>>>(w_res, w_init, w_fin, wT1, wT3);
    k_gemm1<<<(N + 63) / 64, 256, 0, stream>>>(in, wT1, b_res, b_init, out, a1, N);
    k_lfa1<<<(N + 31) / 32, 256, 0, stream>>>(geom, idx, w_g1, b_g1, a1, a2, N);
    k_lfa2_fin<<<(N + 63) / 64, 256, 0, stream>>>(geom, idx, w_g2, b_g2, a2, wT3, b_fin, out, N);
}

// Round 11
// 274.737 us; speedup vs baseline: 1.3391x; 1.2360x over previous
//
#include <hip/hip_runtime.h>

#define DIM 256
#define KNN 16
#define SLOPE 0.2f

typedef unsigned short u16;
typedef __attribute__((ext_vector_type(8))) unsigned short u16x8;
typedef __attribute__((ext_vector_type(4))) unsigned short u16x4;
typedef __attribute__((ext_vector_type(8))) short s16x8;
typedef __attribute__((ext_vector_type(4))) float f32x4;

__device__ __forceinline__ float leaky(float x) { return x >= 0.f ? x : SLOPE * x; }
// f32 -> bf16 (RNE) as raw u16; inputs are finite (no NaN handling needed)
__device__ __forceinline__ u16 f2bu(float f) {
    unsigned int u = __float_as_uint(f);
    u = (u + 0x7FFFu + ((u >> 16) & 1u)) >> 16;
    return (u16)u;
}
__device__ __forceinline__ float bu2f(u16 h) {
    return __uint_as_float(((unsigned int)h) << 16);
}

// ---------------------------------------------------------------------------
// Prep: weights -> bf16 in MFMA fragment order so GEMM kernels load B frags
// directly from global (L2-resident broadcast): no LDS staging for B.
// Fragment (ct, ks): lane l holds w[k = ks*32 + (l>>4)*8 + j][col = ct*16 + (l&15)]
// at wT[((ct*8+ks)*64 + l)*8 + j].
// wT1: ct 0..15 = w_res cols, ct 16..19 = w_init cols. wT3: w_fin cols.
__global__ __launch_bounds__(256) void k_prep(
    const float* __restrict__ w_res, const float* __restrict__ w_init,
    const float* __restrict__ w_fin, u16* __restrict__ wT1, u16* __restrict__ wT3)
{
    const int t = blockIdx.x * 256 + threadIdx.x;
    if (t < 20 * 8 * 64) {               // wT1: 10240 entries x 8 u16
        const int lane = t & 63, frag = t >> 6;
        const int ks = frag & 7, ct = frag >> 3;
        const int col = ct * 16 + (lane & 15);
        const int k0 = ks * 32 + (lane >> 4) * 8;
        u16x8 p;
        #pragma unroll
        for (int j = 0; j < 8; ++j) {
            float v = (col < 256) ? w_res[(size_t)(k0 + j) * 256 + col]
                                  : w_init[(size_t)(k0 + j) * 64 + (col - 256)];
            p[j] = f2bu(v);
        }
        *(u16x8*)(wT1 + (size_t)t * 8) = p;
    } else if (t < 20 * 8 * 64 + 16 * 8 * 64) {  // wT3: 8192 entries x 8 u16
        const int u = t - 20 * 8 * 64;
        const int lane = u & 63, frag = u >> 6;
        const int ks = frag & 7, ct = frag >> 3;
        const int col = ct * 16 + (lane & 15);
        const int k0 = ks * 32 + (lane >> 4) * 8;
        u16x8 p;
        #pragma unroll
        for (int j = 0; j < 8; ++j)
            p[j] = f2bu(w_fin[(size_t)(k0 + j) * 256 + col]);
        *(u16x8*)(wT3 + (size_t)u * 8) = p;
    }
}

#define APAD 264  // 256+8 bf16 elems; 528B row stride -> 16B aligned

// ---------------------------------------------------------------------------
// GEMM1 epilogue helper: one 16-col tile (4 row-tiles x 4 regs) of C.
__device__ __forceinline__ void epi_gemm1(
    int base, int N, int ct, int llow, int lhi, const f32x4* acc4,
    const float* __restrict__ b_res, const float* __restrict__ b_init,
    float* __restrict__ resid, u16* __restrict__ a1)
{
    const int col = ct * 16 + llow;
    if (col < 256) {
        const float bias = b_res[col];
        #pragma unroll
        for (int rt = 0; rt < 4; ++rt)
            #pragma unroll
            for (int r = 0; r < 4; ++r) {
                int row = base + rt * 16 + lhi * 4 + r;
                if (row < N)
                    resid[(size_t)row * DIM + col] = leaky(acc4[rt][r] + bias);
            }
    } else {
        const int c2 = col - 256;
        const float bias = b_init[c2];
        #pragma unroll
        for (int rt = 0; rt < 4; ++rt)
            #pragma unroll
            for (int r = 0; r < 4; ++r) {
                int row = base + rt * 16 + lhi * 4 + r;
                if (row < N)
                    a1[(size_t)row * 64 + c2] = f2bu(leaky(acc4[rt][r] + bias));
            }
    }
}

// GEMM1 [R8 proven]: rows=64/block, cols=320 (0..255 -> resid f32 in d_out,
// 256..319 -> a1 bf16), K=256. A full-K in LDS (1 barrier); B frags direct
// from global wT1. Two passes (3+2 col tiles) cut acc VGPR 80->48;
// __launch_bounds__(256,4) -> 4 blocks/CU (LDS 4x33792 = 132KB <= 160KB).
__global__ __launch_bounds__(256, 4) void k_gemm1(
    const float* __restrict__ in, const u16* __restrict__ wT1,
    const float* __restrict__ b_res, const float* __restrict__ b_init,
    float* __restrict__ resid, u16* __restrict__ a1, int N)
{
    __shared__ u16 A_s[64 * APAD];   // 33792 B
    const int t = threadIdx.x;
    const int base = blockIdx.x * 64;

    {
        const int row = t >> 2, seg = t & 3;
        const int grow = min(base + row, N - 1);
        const float* src = in + (size_t)grow * DIM + seg * 64;
        u16* dst = &A_s[row * APAD + seg * 64];
        #pragma unroll
        for (int j = 0; j < 8; ++j) {
            float4 f0 = *(const float4*)(src + j * 8);
            float4 f1 = *(const float4*)(src + j * 8 + 4);
            u16x8 p;
            p[0] = f2bu(f0.x); p[1] = f2bu(f0.y); p[2] = f2bu(f0.z); p[3] = f2bu(f0.w);
            p[4] = f2bu(f1.x); p[5] = f2bu(f1.y); p[6] = f2bu(f1.z); p[7] = f2bu(f1.w);
            *(u16x8*)(dst + j * 8) = p;
        }
    }
    __syncthreads();  // the only barrier

    const int w = t >> 6, lane = t & 63;
    const int llow = lane & 15, lhi = lane >> 4;

    // ---- pass 0: local col tiles 0..2 ----
    {
        f32x4 acc[3][4];
        #pragma unroll
        for (int i = 0; i < 3; ++i)
            #pragma unroll
            for (int j = 0; j < 4; ++j)
                acc[i][j] = (f32x4){0.f, 0.f, 0.f, 0.f};
        for (int ks = 0; ks < 8; ++ks) {
            s16x8 bfrag[3];
            #pragma unroll
            for (int ci = 0; ci < 3; ++ci) {
                const int ct = w * 5 + ci;
                bfrag[ci] = *(const s16x8*)(wT1 + ((size_t)(ct * 8 + ks) * 64 + lane) * 8);
            }
            s16x8 afrag[4];
            #pragma unroll
            for (int rt = 0; rt < 4; ++rt)
                afrag[rt] = *(const s16x8*)(&A_s[(rt * 16 + llow) * APAD + ks * 32 + lhi * 8]);
            #pragma unroll
            for (int ci = 0; ci < 3; ++ci)
                #pragma unroll
                for (int rt = 0; rt < 4; ++rt)
                    acc[ci][rt] = __builtin_amdgcn_mfma_f32_16x16x32_bf16(
                        afrag[rt], bfrag[ci], acc[ci][rt], 0, 0, 0);
        }
        #pragma unroll
        for (int ci = 0; ci < 3; ++ci)
            epi_gemm1(base, N, w * 5 + ci, llow, lhi, acc[ci], b_res, b_init, resid, a1);
    }
    // ---- pass 1: local col tiles 3..4 ----
    {
        f32x4 acc[2][4];
        #pragma unroll
        for (int i = 0; i < 2; ++i)
            #pragma unroll
            for (int j = 0; j < 4; ++j)
                acc[i][j] = (f32x4){0.f, 0.f, 0.f, 0.f};
        for (int ks = 0; ks < 8; ++ks) {
            s16x8 bfrag[2];
            #pragma unroll
            for (int ci = 0; ci < 2; ++ci) {
                const int ct = w * 5 + 3 + ci;
                bfrag[ci] = *(const s16x8*)(wT1 + ((size_t)(ct * 8 + ks) * 64 + lane) * 8);
            }
            s16x8 afrag[4];
            #pragma unroll
            for (int rt = 0; rt < 4; ++rt)
                afrag[rt] = *(const s16x8*)(&A_s[(rt * 16 + llow) * APAD + ks * 32 + lhi * 8]);
            #pragma unroll
            for (int ci = 0; ci < 2; ++ci)
                #pragma unroll
                for (int rt = 0; rt < 4; ++rt)
                    acc[ci][rt] = __builtin_amdgcn_mfma_f32_16x16x32_bf16(
                        afrag[rt], bfrag[ci], acc[ci][rt], 0, 0, 0);
        }
        #pragma unroll
        for (int ci = 0; ci < 2; ++ci)
            epi_gemm1(base, N, w * 5 + 3 + ci, llow, lhi, acc[ci], b_res, b_init, resid, a1);
    }
}

// ---------------------------------------------------------------------------
// LFA1 [R8 proven]: 32 points/block, 8 lanes/pt, u16x8 gather loads (16B/lane,
// 8 lanes cover the 128B a1 row), k unrolled x2. MLP weights in regs.
__global__ __launch_bounds__(256) void k_lfa1(
    const float* __restrict__ geom, const int* __restrict__ idx,
    const float* __restrict__ w_g1, const float* __restrict__ b_g1,
    const u16* __restrict__ a1, u16* __restrict__ a2, int N)
{
    __shared__ float geom_s[32 * KNN * 4];  // 8 KB
    __shared__ int idx_s[32 * KNN];         // 2 KB
    const int t = threadIdx.x;
    const int base = blockIdx.x * 32;

    {
        size_t mx = (size_t)N * 64 - 4;
        size_t off0 = (size_t)base * 64 + t * 4;
        size_t off1 = off0 + 1024;
        if (off0 > mx) off0 = mx;
        if (off1 > mx) off1 = mx;
        *(float4*)&geom_s[t * 4] = *(const float4*)(geom + off0);
        *(float4*)&geom_s[1024 + t * 4] = *(const float4*)(geom + off1);
        const int imx = N * KNN - 1;
        idx_s[t] = idx[min(base * KNN + t, imx)];
        idx_s[t + 256] = idx[min(base * KNN + 256 + t, imx)];
    }
    __syncthreads();

    const int pt = t >> 3, s = t & 7;
    const int n = base + pt;

    float wr[4][8], bb[8];
    #pragma unroll
    for (int r = 0; r < 4; ++r)
        #pragma unroll
        for (int j = 0; j < 8; ++j)
            wr[r][j] = w_g1[r * 64 + s * 8 + j];
    #pragma unroll
    for (int j = 0; j < 8; ++j) bb[j] = b_g1[s * 8 + j];

    float accM[8];
    #pragma unroll
    for (int j = 0; j < 8; ++j) accM[j] = 0.f;
    const float4* g4 = (const float4*)&geom_s[pt * 64];
    #pragma unroll
    for (int k = 0; k < KNN; ++k) {
        float4 g = g4[k];
        #pragma unroll
        for (int j = 0; j < 8; ++j)
            accM[j] += leaky(g.x * wr[0][j] + g.y * wr[1][j] + g.z * wr[2][j] + g.w * wr[3][j] + bb[j]);
    }

    float accG[8];
    #pragma unroll
    for (int j = 0; j < 8; ++j) accG[j] = 0.f;
    #pragma unroll
    for (int k = 0; k < KNN; k += 2) {
        u16x8 u0 = *(const u16x8*)(a1 + (size_t)idx_s[pt * KNN + k] * 64 + s * 8);
        u16x8 u1 = *(const u16x8*)(a1 + (size_t)idx_s[pt * KNN + k + 1] * 64 + s * 8);
        #pragma unroll
        for (int j = 0; j < 8; ++j) accG[j] += bu2f(u0[j]) + bu2f(u1[j]);
    }

    if (n < N) {
        u16x8 pm, pg;
        #pragma unroll
        for (int j = 0; j < 8; ++j) {
            pm[j] = f2bu(accM[j] * 0.0625f);
            pg[j] = f2bu(accG[j] * 0.0625f);
        }
        *(u16x8*)(a2 + (size_t)n * 128 + s * 8) = pm;
        *(u16x8*)(a2 + (size_t)n * 128 + 64 + s * 8) = pg;
    }
}

// ---------------------------------------------------------------------------
// LFA2 + final GEMM fused [R6 structure, LDS-slimmed]: 64 points/block.
// Identical phases to the R6-proven 111us kernel (staged geom, MLP cols
// 0..127, coalesced gather cols 128..255, MFMA, epilogue+RMW) with ONE
// change: idx_s (4 KB) is dropped — the gather reads idx directly from
// global as int2 per 2-row step (4 lanes of a pt share the load -> L1
// broadcast; no register array, 2 rows in flight). LDS 54272 -> 50176,
// which clears the 163840/3 capacity line with 13 KB margin -> 3 blocks/CU
// co-resident (R1 showed 54272x3 misses the line). VGPR stays ~96-110 so
// the 12 waves/CU actually materialize; __launch_bounds__(256,3) pins it.
// This raises gather-latency-hiding concurrency 1.5x WITHOUT the register
// blowups (R9/R10) or the cache-destroying access-pattern changes (R2/R7).
__global__ __launch_bounds__(256, 3) void k_lfa2_fin(
    const float* __restrict__ geom, const int* __restrict__ idx,
    const float* __restrict__ w_g2, const float* __restrict__ b_g2,
    const u16* __restrict__ a2, const u16* __restrict__ wT3,
    const float* __restrict__ b_fin, float* __restrict__ out, int N)
{
    __shared__ u16 a3_s[64 * APAD];         // 33792 B
    __shared__ float geom_s[64 * KNN * 4];  // 16384 B
    const int t = threadIdx.x;
    const int base = blockIdx.x * 64;

    // stage geom (clamped; clamped rows are >= N and never stored)
    {
        size_t mx = (size_t)N * 64 - 4;
        #pragma unroll
        for (int j = 0; j < 4; ++j) {
            size_t off = (size_t)base * 64 + t * 4 + j * 1024;
            if (off > mx) off = mx;
            *(float4*)&geom_s[t * 4 + j * 1024] = *(const float4*)(geom + off);
        }
    }
    __syncthreads();

    // geom MLP -> a3 cols 0..127. thread = (c = t&127, h = t>>7 -> 32 pts)
    {
        const int c = t & 127, h = t >> 7;
        const float w0 = w_g2[c], w1 = w_g2[128 + c], w2 = w_g2[256 + c],
                    w3 = w_g2[384 + c], bb = b_g2[c];
        for (int p = 0; p < 32; ++p) {
            const int pt = h * 32 + p;
            float acc = 0.f;
            const float4* g4 = (const float4*)&geom_s[pt * 64];
            #pragma unroll
            for (int k = 0; k < KNN; ++k) {
                float4 g = g4[k];
                acc += leaky(g.x * w0 + g.y * w1 + g.z * w2 + g.w * w3 + bb);
            }
            a3_s[pt * APAD + c] = f2bu(acc * 0.0625f);
        }
    }
    // gather -> a3 cols 128..255. thread = (pt = t>>2, q = t&3).
    // idx from GLOBAL (int2 per 2-row step; 4 lanes/pt broadcast). step j:
    // lane q reads u16x8 at row offset j*32 + q*8 -> 64B/pt contiguous.
    {
        const int pt = t >> 2, q = t & 3;
        const int n = min(base + pt, N - 1);
        const int* ip = idx + (size_t)n * KNN;
        float acc[4][8];
        #pragma unroll
        for (int j = 0; j < 4; ++j)
            #pragma unroll
            for (int i = 0; i < 8; ++i) acc[j][i] = 0.f;
        for (int k = 0; k < KNN; k += 2) {  // 2 rows in flight
            int2 kk = *(const int2*)(ip + k);
            const u16* r0 = a2 + (size_t)kk.x * 128;
            const u16* r1 = a2 + (size_t)kk.y * 128;
            u16x8 u0[4], u1[4];
            #pragma unroll
            for (int j = 0; j < 4; ++j) {
                u0[j] = *(const u16x8*)(r0 + j * 32 + q * 8);
                u1[j] = *(const u16x8*)(r1 + j * 32 + q * 8);
            }
            #pragma unroll
            for (int j = 0; j < 4; ++j)
                #pragma unroll
                for (int i = 0; i < 8; ++i)
                    acc[j][i] += bu2f(u0[j][i]) + bu2f(u1[j][i]);
        }
        #pragma unroll
        for (int j = 0; j < 4; ++j) {
            u16x8 p;
            #pragma unroll
            for (int i = 0; i < 8; ++i) p[i] = f2bu(acc[j][i] * 0.0625f);
            *(u16x8*)(&a3_s[pt * APAD + 128 + j * 32 + q * 8]) = p;
        }
    }
    __syncthreads();  // a3_s complete; MFMA loop below is barrier-free

    f32x4 acc[4][4];
    #pragma unroll
    for (int i = 0; i < 4; ++i)
        #pragma unroll
        for (int j = 0; j < 4; ++j)
            acc[i][j] = (f32x4){0.f, 0.f, 0.f, 0.f};

    const int w = t >> 6, lane = t & 63;
    const int llow = lane & 15, lhi = lane >> 4;

    for (int ks = 0; ks < 8; ++ks) {
        s16x8 bfrag[4];
        #pragma unroll
        for (int ci = 0; ci < 4; ++ci) {
            const int ct = w * 4 + ci;
            bfrag[ci] = *(const s16x8*)(wT3 + ((size_t)(ct * 8 + ks) * 64 + lane) * 8);
        }
        s16x8 afrag[4];
        #pragma unroll
        for (int rt = 0; rt < 4; ++rt)
            afrag[rt] = *(const s16x8*)(&a3_s[(rt * 16 + llow) * APAD + ks * 32 + lhi * 8]);
        #pragma unroll
        for (int ci = 0; ci < 4; ++ci)
            #pragma unroll
            for (int rt = 0; rt < 4; ++rt)
                acc[rt][ci] = __builtin_amdgcn_mfma_f32_16x16x32_bf16(
                    afrag[rt], bfrag[ci], acc[rt][ci], 0, 0, 0);
    }

    #pragma unroll
    for (int ci = 0; ci < 4; ++ci) {
        const int ct = w * 4 + ci;
        const int col = ct * 16 + llow;
        const float bias = b_fin[col];
        #pragma unroll
        for (int rt = 0; rt < 4; ++rt)
            #pragma unroll
            for (int r = 0; r < 4; ++r) {
                int row = base + rt * 16 + lhi * 4 + r;
                if (row < N) {
                    size_t o = (size_t)row * DIM + col;
                    out[o] = leaky(acc[rt][ci][r] + bias) + out[o];
                }
            }
    }
}

// ---------------------------------------------------------------------------
extern "C" void kernel_launch(void* const* d_in, const int* in_sizes, int n_in,
                              void* d_out, int out_size, void* d_ws, size_t ws_size,
                              hipStream_t stream) {
    const float* in    = (const float*)d_in[0];
    const float* geom  = (const float*)d_in[1];
    const int*   idx   = (const int*)d_in[2];
    const float* w_res = (const float*)d_in[3];
    const float* b_res = (const float*)d_in[4];
    const float* w_init= (const float*)d_in[5];
    const float* b_init= (const float*)d_in[6];
    const float* w_g1  = (const float*)d_in[7];
    const float* b_g1  = (const float*)d_in[8];
    const float* w_g2  = (const float*)d_in[9];
    const float* b_g2  = (const float*)d_in[10];
    const float* w_fin = (const float*)d_in[11];
    const float* b_fin = (const float*)d_in[12];
    float* out = (float*)d_out;

    const int N = in_sizes[0] / DIM;  // 50000

    // ws: a1 N*64 bf16 | a2 N*128 bf16 | wT1 320*256 bf16 | wT3 256*256 bf16
    char* ws = (char*)d_ws;
    u16* a1  = (u16*)ws;
    u16* a2  = a1 + (size_t)N * 64;
    u16* wT1 = a2 + (size_t)N * 128;
    u16* wT3 = wT1 + 320 * 256;

    k_prep<<<72, 256, 0, stream>>>(w_res, w_init, w_fin, wT1, wT3);
    k_gemm1<<<(N + 63) / 64, 256, 0, stream>>>(in, wT1, b_res, b_init, out, a1, N);
    k_lfa1<<<(N + 31) / 32, 256, 0, stream>>>(geom, idx, w_g1, b_g1, a1, a2, N);
    k_lfa2_fin<<<(N + 63) / 64, 256, 0, stream>>>(geom, idx, w_g2, b_g2, a2, wT3, b_fin, out, N);
}

// Round 12
// 261.730 us; speedup vs baseline: 1.4056x; 1.0497x over previous
//
#include <hip/hip_runtime.h>

#define DIM 256
#define KNN 16
#define SLOPE 0.2f

typedef unsigned short u16;
typedef __attribute__((ext_vector_type(8))) unsigned short u16x8;
typedef __attribute__((ext_vector_type(4))) unsigned short u16x4;
typedef __attribute__((ext_vector_type(8))) short s16x8;
typedef __attribute__((ext_vector_type(4))) float f32x4;

__device__ __forceinline__ float leaky(float x) { return x >= 0.f ? x : SLOPE * x; }
// f32 -> bf16 (RNE) as raw u16; inputs are finite (no NaN handling needed)
__device__ __forceinline__ u16 f2bu(float f) {
    unsigned int u = __float_as_uint(f);
    u = (u + 0x7FFFu + ((u >> 16) & 1u)) >> 16;
    return (u16)u;
}
__device__ __forceinline__ float bu2f(u16 h) {
    return __uint_as_float(((unsigned int)h) << 16);
}

// ---------------------------------------------------------------------------
// Prep: weights -> bf16 in MFMA fragment order so GEMM kernels load B frags
// directly from global (L2-resident broadcast): no LDS staging for B.
// wT1: ct 0..15 = w_res cols, ct 16..19 = w_init cols. wT3: w_fin cols.
__global__ __launch_bounds__(256) void k_prep(
    const float* __restrict__ w_res, const float* __restrict__ w_init,
    const float* __restrict__ w_fin, u16* __restrict__ wT1, u16* __restrict__ wT3)
{
    const int t = blockIdx.x * 256 + threadIdx.x;
    if (t < 20 * 8 * 64) {               // wT1: 10240 entries x 8 u16
        const int lane = t & 63, frag = t >> 6;
        const int ks = frag & 7, ct = frag >> 3;
        const int col = ct * 16 + (lane & 15);
        const int k0 = ks * 32 + (lane >> 4) * 8;
        u16x8 p;
        #pragma unroll
        for (int j = 0; j < 8; ++j) {
            float v = (col < 256) ? w_res[(size_t)(k0 + j) * 256 + col]
                                  : w_init[(size_t)(k0 + j) * 64 + (col - 256)];
            p[j] = f2bu(v);
        }
        *(u16x8*)(wT1 + (size_t)t * 8) = p;
    } else if (t < 20 * 8 * 64 + 16 * 8 * 64) {  // wT3: 8192 entries x 8 u16
        const int u = t - 20 * 8 * 64;
        const int lane = u & 63, frag = u >> 6;
        const int ks = frag & 7, ct = frag >> 3;
        const int col = ct * 16 + (lane & 15);
        const int k0 = ks * 32 + (lane >> 4) * 8;
        u16x8 p;
        #pragma unroll
        for (int j = 0; j < 8; ++j)
            p[j] = f2bu(w_fin[(size_t)(k0 + j) * 256 + col]);
        *(u16x8*)(wT3 + (size_t)u * 8) = p;
    }
}

#define APAD 264  // 256+8 bf16 elems; 528B row stride -> 16B aligned

// ---------------------------------------------------------------------------
// GEMM1 epilogue: one 16-col tile. resid goes to FRAGMENT-LINEAR ws buffer
// [blk][ct][rt][r][lane] f32 when residf != null: each (rt,r) store is 64
// lanes x 4B contiguous = one 256B coalesced transaction (vs 4 x 64B
// row-major), no row guards (buffer padded to Np rows). Fallback: row-major
// f32 to resid_out (old RMW scheme). a1 stores unguarded (Np-padded).
__device__ __forceinline__ void epi_gemm1(
    int base, int N, int ct, int lane, const f32x4* acc4,
    const float* __restrict__ b_res, const float* __restrict__ b_init,
    float* __restrict__ resid_out, float* __restrict__ residf,
    u16* __restrict__ a1)
{
    const int llow = lane & 15, lhi = lane >> 4;
    const int col = ct * 16 + llow;
    if (col < 256) {
        const float bias = b_res[col];
        if (residf) {
            float* dst = residf + ((size_t)(base >> 6) * 16 + ct) * 1024 + lane;
            #pragma unroll
            for (int rt = 0; rt < 4; ++rt)
                #pragma unroll
                for (int r = 0; r < 4; ++r)
                    dst[(rt * 4 + r) * 64] = leaky(acc4[rt][r] + bias);
        } else {
            #pragma unroll
            for (int rt = 0; rt < 4; ++rt)
                #pragma unroll
                for (int r = 0; r < 4; ++r) {
                    int row = base + rt * 16 + lhi * 4 + r;
                    if (row < N)
                        resid_out[(size_t)row * DIM + col] = leaky(acc4[rt][r] + bias);
                }
        }
    } else {
        const int c2 = col - 256;
        const float bias = b_init[c2];
        #pragma unroll
        for (int rt = 0; rt < 4; ++rt)
            #pragma unroll
            for (int r = 0; r < 4; ++r) {
                int row = base + rt * 16 + lhi * 4 + r;  // < Np, buffer padded
                a1[(size_t)row * 64 + c2] = f2bu(leaky(acc4[rt][r] + bias));
            }
    }
}

// GEMM1 [R8 proven + coalesced resid]: rows=64/block, cols=320, K=256.
// A full-K in LDS (1 barrier); B frags direct from global wT1. Two passes
// (3+2 col tiles); __launch_bounds__(256,4) -> 4 blocks/CU.
__global__ __launch_bounds__(256, 4) void k_gemm1(
    const float* __restrict__ in, const u16* __restrict__ wT1,
    const float* __restrict__ b_res, const float* __restrict__ b_init,
    float* __restrict__ resid_out, float* __restrict__ residf,
    u16* __restrict__ a1, int N)
{
    __shared__ u16 A_s[64 * APAD];   // 33792 B
    const int t = threadIdx.x;
    const int base = blockIdx.x * 64;

    {
        const int row = t >> 2, seg = t & 3;
        const int grow = min(base + row, N - 1);
        const float* src = in + (size_t)grow * DIM + seg * 64;
        u16* dst = &A_s[row * APAD + seg * 64];
        #pragma unroll
        for (int j = 0; j < 8; ++j) {
            float4 f0 = *(const float4*)(src + j * 8);
            float4 f1 = *(const float4*)(src + j * 8 + 4);
            u16x8 p;
            p[0] = f2bu(f0.x); p[1] = f2bu(f0.y); p[2] = f2bu(f0.z); p[3] = f2bu(f0.w);
            p[4] = f2bu(f1.x); p[5] = f2bu(f1.y); p[6] = f2bu(f1.z); p[7] = f2bu(f1.w);
            *(u16x8*)(dst + j * 8) = p;
        }
    }
    __syncthreads();  // the only barrier

    const int w = t >> 6, lane = t & 63;
    const int llow = lane & 15, lhi = lane >> 4;

    // ---- pass 0: local col tiles 0..2 ----
    {
        f32x4 acc[3][4];
        #pragma unroll
        for (int i = 0; i < 3; ++i)
            #pragma unroll
            for (int j = 0; j < 4; ++j)
                acc[i][j] = (f32x4){0.f, 0.f, 0.f, 0.f};
        for (int ks = 0; ks < 8; ++ks) {
            s16x8 bfrag[3];
            #pragma unroll
            for (int ci = 0; ci < 3; ++ci) {
                const int ct = w * 5 + ci;
                bfrag[ci] = *(const s16x8*)(wT1 + ((size_t)(ct * 8 + ks) * 64 + lane) * 8);
            }
            s16x8 afrag[4];
            #pragma unroll
            for (int rt = 0; rt < 4; ++rt)
                afrag[rt] = *(const s16x8*)(&A_s[(rt * 16 + llow) * APAD + ks * 32 + lhi * 8]);
            #pragma unroll
            for (int ci = 0; ci < 3; ++ci)
                #pragma unroll
                for (int rt = 0; rt < 4; ++rt)
                    acc[ci][rt] = __builtin_amdgcn_mfma_f32_16x16x32_bf16(
                        afrag[rt], bfrag[ci], acc[ci][rt], 0, 0, 0);
        }
        #pragma unroll
        for (int ci = 0; ci < 3; ++ci)
            epi_gemm1(base, N, w * 5 + ci, lane, acc[ci], b_res, b_init, resid_out, residf, a1);
    }
    // ---- pass 1: local col tiles 3..4 ----
    {
        f32x4 acc[2][4];
        #pragma unroll
        for (int i = 0; i < 2; ++i)
            #pragma unroll
            for (int j = 0; j < 4; ++j)
                acc[i][j] = (f32x4){0.f, 0.f, 0.f, 0.f};
        for (int ks = 0; ks < 8; ++ks) {
            s16x8 bfrag[2];
            #pragma unroll
            for (int ci = 0; ci < 2; ++ci) {
                const int ct = w * 5 + 3 + ci;
                bfrag[ci] = *(const s16x8*)(wT1 + ((size_t)(ct * 8 + ks) * 64 + lane) * 8);
            }
            s16x8 afrag[4];
            #pragma unroll
            for (int rt = 0; rt < 4; ++rt)
                afrag[rt] = *(const s16x8*)(&A_s[(rt * 16 + llow) * APAD + ks * 32 + lhi * 8]);
            #pragma unroll
            for (int ci = 0; ci < 2; ++ci)
                #pragma unroll
                for (int rt = 0; rt < 4; ++rt)
                    acc[ci][rt] = __builtin_amdgcn_mfma_f32_16x16x32_bf16(
                        afrag[rt], bfrag[ci], acc[ci][rt], 0, 0, 0);
        }
        #pragma unroll
        for (int ci = 0; ci < 2; ++ci)
            epi_gemm1(base, N, w * 5 + 3 + ci, lane, acc[ci], b_res, b_init, resid_out, residf, a1);
    }
}

// ---------------------------------------------------------------------------
// LFA1 [R8 proven]: 32 points/block, 8 lanes/pt, u16x8 gather loads (16B/lane,
// 8 lanes cover the 128B a1 row), k unrolled x2. MLP weights in regs.
__global__ __launch_bounds__(256) void k_lfa1(
    const float* __restrict__ geom, const int* __restrict__ idx,
    const float* __restrict__ w_g1, const float* __restrict__ b_g1,
    const u16* __restrict__ a1, u16* __restrict__ a2, int N)
{
    __shared__ float geom_s[32 * KNN * 4];  // 8 KB
    __shared__ int idx_s[32 * KNN];         // 2 KB
    const int t = threadIdx.x;
    const int base = blockIdx.x * 32;

    {
        size_t mx = (size_t)N * 64 - 4;
        size_t off0 = (size_t)base * 64 + t * 4;
        size_t off1 = off0 + 1024;
        if (off0 > mx) off0 = mx;
        if (off1 > mx) off1 = mx;
        *(float4*)&geom_s[t * 4] = *(const float4*)(geom + off0);
        *(float4*)&geom_s[1024 + t * 4] = *(const float4*)(geom + off1);
        const int imx = N * KNN - 1;
        idx_s[t] = idx[min(base * KNN + t, imx)];
        idx_s[t + 256] = idx[min(base * KNN + 256 + t, imx)];
    }
    __syncthreads();

    const int pt = t >> 3, s = t & 7;
    const int n = base + pt;

    float wr[4][8], bb[8];
    #pragma unroll
    for (int r = 0; r < 4; ++r)
        #pragma unroll
        for (int j = 0; j < 8; ++j)
            wr[r][j] = w_g1[r * 64 + s * 8 + j];
    #pragma unroll
    for (int j = 0; j < 8; ++j) bb[j] = b_g1[s * 8 + j];

    float accM[8];
    #pragma unroll
    for (int j = 0; j < 8; ++j) accM[j] = 0.f;
    const float4* g4 = (const float4*)&geom_s[pt * 64];
    #pragma unroll
    for (int k = 0; k < KNN; ++k) {
        float4 g = g4[k];
        #pragma unroll
        for (int j = 0; j < 8; ++j)
            accM[j] += leaky(g.x * wr[0][j] + g.y * wr[1][j] + g.z * wr[2][j] + g.w * wr[3][j] + bb[j]);
    }

    float accG[8];
    #pragma unroll
    for (int j = 0; j < 8; ++j) accG[j] = 0.f;
    #pragma unroll
    for (int k = 0; k < KNN; k += 2) {
        u16x8 u0 = *(const u16x8*)(a1 + (size_t)idx_s[pt * KNN + k] * 64 + s * 8);
        u16x8 u1 = *(const u16x8*)(a1 + (size_t)idx_s[pt * KNN + k + 1] * 64 + s * 8);
        #pragma unroll
        for (int j = 0; j < 8; ++j) accG[j] += bu2f(u0[j]) + bu2f(u1[j]);
    }

    if (n < N) {
        u16x8 pm, pg;
        #pragma unroll
        for (int j = 0; j < 8; ++j) {
            pm[j] = f2bu(accM[j] * 0.0625f);
            pg[j] = f2bu(accG[j] * 0.0625f);
        }
        *(u16x8*)(a2 + (size_t)n * 128 + s * 8) = pm;
        *(u16x8*)(a2 + (size_t)n * 128 + 64 + s * 8) = pg;
    }
}

// ---------------------------------------------------------------------------
// LFA2 + final GEMM fused [R11 proven + coalesced resid read]: 64 pts/block.
// Staged geom MLP (cols 0..127), coalesced global-idx gather (cols 128..255),
// MFMA vs wT3. Epilogue: when residf != null, read resid from the
// fragment-linear buffer (256B coalesced per (rt,r)) and write out PURELY
// (no RMW read of out). Fallback: RMW on out (resid row-major in out).
// LDS 50176 -> 3 blocks/CU (R11: 97us, occupancy 21.5%).
__global__ __launch_bounds__(256, 3) void k_lfa2_fin(
    const float* __restrict__ geom, const int* __restrict__ idx,
    const float* __restrict__ w_g2, const float* __restrict__ b_g2,
    const u16* __restrict__ a2, const u16* __restrict__ wT3,
    const float* __restrict__ b_fin, const float* __restrict__ residf,
    float* __restrict__ out, int N)
{
    __shared__ u16 a3_s[64 * APAD];         // 33792 B
    __shared__ float geom_s[64 * KNN * 4];  // 16384 B
    const int t = threadIdx.x;
    const int base = blockIdx.x * 64;

    // stage geom (clamped; clamped rows are >= N and never stored)
    {
        size_t mx = (size_t)N * 64 - 4;
        #pragma unroll
        for (int j = 0; j < 4; ++j) {
            size_t off = (size_t)base * 64 + t * 4 + j * 1024;
            if (off > mx) off = mx;
            *(float4*)&geom_s[t * 4 + j * 1024] = *(const float4*)(geom + off);
        }
    }
    __syncthreads();

    // geom MLP -> a3 cols 0..127. thread = (c = t&127, h = t>>7 -> 32 pts)
    {
        const int c = t & 127, h = t >> 7;
        const float w0 = w_g2[c], w1 = w_g2[128 + c], w2 = w_g2[256 + c],
                    w3 = w_g2[384 + c], bb = b_g2[c];
        for (int p = 0; p < 32; ++p) {
            const int pt = h * 32 + p;
            float acc = 0.f;
            const float4* g4 = (const float4*)&geom_s[pt * 64];
            #pragma unroll
            for (int k = 0; k < KNN; ++k) {
                float4 g = g4[k];
                acc += leaky(g.x * w0 + g.y * w1 + g.z * w2 + g.w * w3 + bb);
            }
            a3_s[pt * APAD + c] = f2bu(acc * 0.0625f);
        }
    }
    // gather -> a3 cols 128..255. thread = (pt = t>>2, q = t&3).
    // idx from GLOBAL (int2 per 2-row step; 4 lanes/pt broadcast). step j:
    // lane q reads u16x8 at row offset j*32 + q*8 -> 64B/pt contiguous.
    {
        const int pt = t >> 2, q = t & 3;
        const int n = min(base + pt, N - 1);
        const int* ip = idx + (size_t)n * KNN;
        float acc[4][8];
        #pragma unroll
        for (int j = 0; j < 4; ++j)
            #pragma unroll
            for (int i = 0; i < 8; ++i) acc[j][i] = 0.f;
        for (int k = 0; k < KNN; k += 2) {  // 2 rows in flight
            int2 kk = *(const int2*)(ip + k);
            const u16* r0 = a2 + (size_t)kk.x * 128;
            const u16* r1 = a2 + (size_t)kk.y * 128;
            u16x8 u0[4], u1[4];
            #pragma unroll
            for (int j = 0; j < 4; ++j) {
                u0[j] = *(const u16x8*)(r0 + j * 32 + q * 8);
                u1[j] = *(const u16x8*)(r1 + j * 32 + q * 8);
            }
            #pragma unroll
            for (int j = 0; j < 4; ++j)
                #pragma unroll
                for (int i = 0; i < 8; ++i)
                    acc[j][i] += bu2f(u0[j][i]) + bu2f(u1[j][i]);
        }
        #pragma unroll
        for (int j = 0; j < 4; ++j) {
            u16x8 p;
            #pragma unroll
            for (int i = 0; i < 8; ++i) p[i] = f2bu(acc[j][i] * 0.0625f);
            *(u16x8*)(&a3_s[pt * APAD + 128 + j * 32 + q * 8]) = p;
        }
    }
    __syncthreads();  // a3_s complete; MFMA loop below is barrier-free

    f32x4 acc[4][4];
    #pragma unroll
    for (int i = 0; i < 4; ++i)
        #pragma unroll
        for (int j = 0; j < 4; ++j)
            acc[i][j] = (f32x4){0.f, 0.f, 0.f, 0.f};

    const int w = t >> 6, lane = t & 63;
    const int llow = lane & 15, lhi = lane >> 4;

    for (int ks = 0; ks < 8; ++ks) {
        s16x8 bfrag[4];
        #pragma unroll
        for (int ci = 0; ci < 4; ++ci) {
            const int ct = w * 4 + ci;
            bfrag[ci] = *(const s16x8*)(wT3 + ((size_t)(ct * 8 + ks) * 64 + lane) * 8);
        }
        s16x8 afrag[4];
        #pragma unroll
        for (int rt = 0; rt < 4; ++rt)
            afrag[rt] = *(const s16x8*)(&a3_s[(rt * 16 + llow) * APAD + ks * 32 + lhi * 8]);
        #pragma unroll
        for (int ci = 0; ci < 4; ++ci)
            #pragma unroll
            for (int rt = 0; rt < 4; ++rt)
                acc[rt][ci] = __builtin_amdgcn_mfma_f32_16x16x32_bf16(
                    afrag[rt], bfrag[ci], acc[rt][ci], 0, 0, 0);
    }

    if (residf) {
        const float* rfb = residf + (size_t)(base >> 6) * 16 * 1024 + lane;
        #pragma unroll
        for (int ci = 0; ci < 4; ++ci) {
            const int ct = w * 4 + ci;
            const int col = ct * 16 + llow;
            const float bias = b_fin[col];
            const float* rfc = rfb + ct * 1024;
            #pragma unroll
            for (int rt = 0; rt < 4; ++rt)
                #pragma unroll
                for (int r = 0; r < 4; ++r) {
                    int row = base + rt * 16 + lhi * 4 + r;
                    if (row < N)
                        out[(size_t)row * DIM + col] =
                            leaky(acc[rt][ci][r] + bias) + rfc[(rt * 4 + r) * 64];
                }
        }
    } else {
        #pragma unroll
        for (int ci = 0; ci < 4; ++ci) {
            const int ct = w * 4 + ci;
            const int col = ct * 16 + llow;
            const float bias = b_fin[col];
            #pragma unroll
            for (int rt = 0; rt < 4; ++rt)
                #pragma unroll
                for (int r = 0; r < 4; ++r) {
                    int row = base + rt * 16 + lhi * 4 + r;
                    if (row < N) {
                        size_t o = (size_t)row * DIM + col;
                        out[o] = leaky(acc[rt][ci][r] + bias) + out[o];
                    }
                }
        }
    }
}

// ---------------------------------------------------------------------------
extern "C" void kernel_launch(void* const* d_in, const int* in_sizes, int n_in,
                              void* d_out, int out_size, void* d_ws, size_t ws_size,
                              hipStream_t stream) {
    const float* in    = (const float*)d_in[0];
    const float* geom  = (const float*)d_in[1];
    const int*   idx   = (const int*)d_in[2];
    const float* w_res = (const float*)d_in[3];
    const float* b_res = (const float*)d_in[4];
    const float* w_init= (const float*)d_in[5];
    const float* b_init= (const float*)d_in[6];
    const float* w_g1  = (const float*)d_in[7];
    const float* b_g1  = (const float*)d_in[8];
    const float* w_g2  = (const float*)d_in[9];
    const float* b_g2  = (const float*)d_in[10];
    const float* w_fin = (const float*)d_in[11];
    const float* b_fin = (const float*)d_in[12];
    float* out = (float*)d_out;

    const int N = in_sizes[0] / DIM;      // 50000
    const int nblk = (N + 63) / 64;       // 782
    const int Np = nblk * 64;             // 50048 (padded rows)

    // frag layout: residf f32 Np*256 | a1 u16 Np*64 | a2 u16 N*128 | wT1 | wT3
    const size_t need_frag = (size_t)Np * 256 * 4 + (size_t)Np * 64 * 2
                           + (size_t)N * 128 * 2 + (320 * 256 + 256 * 256) * 2;
    const bool frag = ws_size >= need_frag;

    char* ws = (char*)d_ws;
    float* residf = nullptr;
    u16 *a1, *a2, *wT1, *wT3;
    if (frag) {
        residf = (float*)ws;
        a1  = (u16*)(ws + (size_t)Np * 256 * 4);
        a2  = a1 + (size_t)Np * 64;
        wT1 = a2 + (size_t)N * 128;
        wT3 = wT1 + 320 * 256;
    } else {
        a1  = (u16*)ws;
        a2  = a1 + (size_t)Np * 64;
        wT1 = a2 + (size_t)N * 128;
        wT3 = wT1 + 320 * 256;
    }

    k_prep<<<72, 256, 0, stream>>>(w_res, w_init, w_fin, wT1, wT3);
    k_gemm1<<<nblk, 256, 0, stream>>>(in, wT1, b_res, b_init, out, residf, a1, N);
    k_lfa1<<<(N + 31) / 32, 256, 0, stream>>>(geom, idx, w_g1, b_g1, a1, a2, N);
    k_lfa2_fin<<<nblk, 256, 0, stream>>>(geom, idx, w_g2, b_g2, a2, wT3, b_fin, residf, out, N);
}